// Round 1
// baseline (28.053 us; speedup 1.0000x reference)
//
#include <hip/hip_runtime.h>

__device__ __forceinline__ void ik_solve(float x, float y,
                                         float c0, float c1,
                                         float l1s, float l2s,
                                         float sumsq, float rden,
                                         float& t1, float& t2) {
    float xs = x * c0;
    float ys = y * c1;
    float dis = xs * xs + ys * ys + 1e-6f;
    float arg = (dis - sumsq) * rden;
    arg = fminf(fmaxf(arg, -1.0f), 1.0f);
    t2 = acosf(arg);
    // cos(t2) == arg, sin(t2) == sqrt(1 - arg^2)  (t2 in [0, pi] so sin >= 0)
    float st2 = sqrtf(fmaxf(1.0f - arg * arg, 0.0f));
    float num = ys * fmaf(l2s, arg, l1s) - xs * l2s * st2;
    float a1 = num / dis;
    a1 = fminf(fmaxf(a1, -1.0f), 1.0f);
    t1 = asinf(a1);
}

__global__ __launch_bounds__(256)
void Forward_Model_27616639714074_kernel(const float* __restrict__ in,
                                         const float* __restrict__ w,
                                         float* __restrict__ out,
                                         long long n,        // floats per mult (= SIZE*2)
                                         int n_mults) {
    long long tid = (long long)blockIdx.x * blockDim.x + threadIdx.x;
    long long stride = (long long)gridDim.x * blockDim.x;
    long long n4 = n >> 2;               // float4 groups

    for (int ii = 0; ii < n_mults; ++ii) {
        // forward value of c = clip(round(w), 0.001, None); jnp.round = rint
        float c0  = fmaxf(rintf(w[ii * 4 + 0]), 0.001f);
        float c1  = fmaxf(rintf(w[ii * 4 + 1]), 0.001f);
        float l1s = 0.5f * fmaxf(rintf(w[ii * 4 + 2]), 0.001f);
        float l2s = 0.5f * fmaxf(rintf(w[ii * 4 + 3]), 0.001f);
        float sumsq = l1s * l1s + l2s * l2s;
        float rden  = 1.0f / (2.0f * l1s * l2s + 1e-6f);
        float* outp = out + (long long)ii * n;

        const float4* in4 = reinterpret_cast<const float4*>(in);
        float4* out4 = reinterpret_cast<float4*>(outp);

        for (long long i = tid; i < n4; i += stride) {
            float4 v = in4[i];
            float4 r;
            ik_solve(v.x, v.y, c0, c1, l1s, l2s, sumsq, rden, r.x, r.y);
            ik_solve(v.z, v.w, c0, c1, l1s, l2s, sumsq, rden, r.z, r.w);
            out4[i] = r;
        }

        // tail: any leftover (x,y) pair past the float4 region (n always even)
        long long pair_start = (n4 << 2) >> 1;   // first un-processed pair index
        long long n_pairs = n >> 1;
        for (long long p = pair_start + tid; p < n_pairs; p += stride) {
            float x = in[p * 2 + 0];
            float y = in[p * 2 + 1];
            float t1, t2;
            ik_solve(x, y, c0, c1, l1s, l2s, sumsq, rden, t1, t2);
            outp[p * 2 + 0] = t1;
            outp[p * 2 + 1] = t2;
        }
    }
}

extern "C" void kernel_launch(void* const* d_in, const int* in_sizes, int n_in,
                              void* d_out, int out_size, void* d_ws, size_t ws_size,
                              hipStream_t stream) {
    const float* in = (const float*)d_in[0];
    const float* w  = (const float*)d_in[1];
    float* out = (float*)d_out;

    long long n = in_sizes[0];           // SIZE*2 floats
    int n_mults = in_sizes[1] / 4;       // N_MULTS

    int block = 256;
    long long n4 = n >> 2;
    long long want = (n4 + block - 1) / block;
    int grid = (int)(want < 2048 ? (want > 0 ? want : 1) : 2048);

    Forward_Model_27616639714074_kernel<<<grid, block, 0, stream>>>(
        in, w, out, n, n_mults);
}

// Round 2
// 27.231 us; speedup vs baseline: 1.0302x; 1.0302x over previous
//
#include <hip/hip_runtime.h>

// Abramowitz-Stegun 4.4.45: acos(x) ~ sqrt(1-x)*(a0 + a1 x + a2 x^2 + a3 x^3),
// |err| <= 6.8e-5 on [0,1]. Branchless extension to [-1,1].
__device__ __forceinline__ float poly_p(float a) {
    return fmaf(a, fmaf(a, fmaf(a, -0.0187293f, 0.0742610f), -0.2121144f),
                1.5707288f);
}

__device__ __forceinline__ float fast_acos(float x) {
    float a = fabsf(x);
    float r = sqrtf(fmaxf(1.0f - a, 0.0f)) * poly_p(a);
    return x >= 0.0f ? r : 3.14159265f - r;   // v_cndmask
}

__device__ __forceinline__ float fast_asin(float x) {
    float a = fabsf(x);
    float r = 1.5707963f - sqrtf(fmaxf(1.0f - a, 0.0f)) * poly_p(a);
    return copysignf(r, x);
}

__device__ __forceinline__ void ik_solve(float x, float y,
                                         float c0, float c1,
                                         float l1s, float l2s,
                                         float sumsq, float rden,
                                         float& t1, float& t2) {
    float xs = x * c0;
    float ys = y * c1;
    float dis = fmaf(xs, xs, fmaf(ys, ys, 1e-6f));
    float arg = (dis - sumsq) * rden;
    arg = fminf(fmaxf(arg, -1.0f), 1.0f);
    t2 = fast_acos(arg);
    // cos(t2) == arg, sin(t2) == sqrt(1 - arg^2)  (t2 in [0, pi] so sin >= 0)
    float st2 = sqrtf(fmaxf(fmaf(-arg, arg, 1.0f), 0.0f));
    float num = ys * fmaf(l2s, arg, l1s) - xs * l2s * st2;
    float a1 = num * __builtin_amdgcn_rcpf(dis);   // dis >= 1e-6, approx rcp ok
    a1 = fminf(fmaxf(a1, -1.0f), 1.0f);
    t1 = fast_asin(a1);
}

__global__ __launch_bounds__(256)
void Forward_Model_27616639714074_kernel(const float* __restrict__ in,
                                         const float* __restrict__ w,
                                         float* __restrict__ out,
                                         long long n,        // floats per mult (= SIZE*2)
                                         int n_mults) {
    long long tid = (long long)blockIdx.x * blockDim.x + threadIdx.x;
    long long stride = (long long)gridDim.x * blockDim.x;
    long long n4 = n >> 2;               // float4 groups

    for (int ii = 0; ii < n_mults; ++ii) {
        // forward value of c = clip(round(w), 0.001, None); jnp.round = rint
        float c0  = fmaxf(rintf(w[ii * 4 + 0]), 0.001f);
        float c1  = fmaxf(rintf(w[ii * 4 + 1]), 0.001f);
        float l1s = 0.5f * fmaxf(rintf(w[ii * 4 + 2]), 0.001f);
        float l2s = 0.5f * fmaxf(rintf(w[ii * 4 + 3]), 0.001f);
        float sumsq = l1s * l1s + l2s * l2s;
        float rden  = 1.0f / (2.0f * l1s * l2s + 1e-6f);
        float* outp = out + (long long)ii * n;

        const float4* in4 = reinterpret_cast<const float4*>(in);
        float4* out4 = reinterpret_cast<float4*>(outp);

        #pragma unroll 2
        for (long long i = tid; i < n4; i += stride) {
            float4 v = in4[i];
            float4 r;
            ik_solve(v.x, v.y, c0, c1, l1s, l2s, sumsq, rden, r.x, r.y);
            ik_solve(v.z, v.w, c0, c1, l1s, l2s, sumsq, rden, r.z, r.w);
            out4[i] = r;
        }

        // tail: any leftover (x,y) pair past the float4 region (n always even)
        long long pair_start = (n4 << 2) >> 1;   // first un-processed pair index
        long long n_pairs = n >> 1;
        for (long long p = pair_start + tid; p < n_pairs; p += stride) {
            float x = in[p * 2 + 0];
            float y = in[p * 2 + 1];
            float t1, t2;
            ik_solve(x, y, c0, c1, l1s, l2s, sumsq, rden, t1, t2);
            outp[p * 2 + 0] = t1;
            outp[p * 2 + 1] = t2;
        }
    }
}

extern "C" void kernel_launch(void* const* d_in, const int* in_sizes, int n_in,
                              void* d_out, int out_size, void* d_ws, size_t ws_size,
                              hipStream_t stream) {
    const float* in = (const float*)d_in[0];
    const float* w  = (const float*)d_in[1];
    float* out = (float*)d_out;

    long long n = in_sizes[0];           // SIZE*2 floats
    int n_mults = in_sizes[1] / 4;       // N_MULTS

    int block = 256;
    long long n4 = n >> 2;
    long long want = (n4 + block - 1) / block;
    int grid = (int)(want < 2048 ? (want > 0 ? want : 1) : 2048);

    Forward_Model_27616639714074_kernel<<<grid, block, 0, stream>>>(
        in, w, out, n, n_mults);
}